// Round 5
// baseline (281.899 us; speedup 1.0000x reference)
//
#include <hip/hip_runtime.h>
#include <hip/hip_bf16.h>

// DKM fused (round 5): 3-buffer depth-2 pipeline with counted vmcnt (T4) + setprio (T5).
// d2 = ||x||^2 + ||c||^2 - 2 X C^T ; argmin -> idx/centroids ; softmax(-d2) -> loss.
// X.C^T via hi/lo f16 split: Xhi.Chi + Xhi.Clo + Xlo.Chi (fp32 MFMA accum).
// Main loop per stage s: vmcnt(6) [retire tile s, keep s+1 in flight] -> s_barrier ->
// issue DMA for s+2 into buf (s+2)%3 -> ds_read/MFMA on buf s%3. Never drains to 0
// except the last stage. Issue-after-barrier makes writer buf != any reader buf.
// Out layout (float32): [centroids 32768*512][idx 32768][loss 1]

#define NN 32768
#define DD 512
#define KK 1024
#define NSTG 128
#define IDX_OFF ((size_t)NN * DD)
#define LOSS_OFF ((size_t)NN * DD + NN)

typedef _Float16 f16x8 __attribute__((ext_vector_type(8)));
typedef _Float16 f16x4 __attribute__((ext_vector_type(4)));
typedef float f32x4 __attribute__((ext_vector_type(4)));

// ---- workspace layout (f16 element offsets into ws) ----
#define XHI_OFF ((size_t)0)
#define XLO_OFF ((size_t)NN * DD)
#define CHI_OFF ((size_t)2 * NN * DD)
#define CLO_OFF ((size_t)2 * NN * DD + (size_t)KK * DD)
#define F16_TOTAL ((size_t)2 * NN * DD + (size_t)2 * KK * DD)
#define WS_NEEDED (F16_TOTAL * 2 + (size_t)(NN + KK) * 4)

__device__ __forceinline__ void gll16(const _Float16* g, void* lds) {
  // async global->LDS DMA, 16B/lane; LDS dest = wave-uniform base + lane*16
  __builtin_amdgcn_global_load_lds((const __attribute__((address_space(1))) void*)g,
                                   (__attribute__((address_space(3))) void*)lds, 16, 0, 0);
}

// ================= prepass: fp32 -> f16 hi/lo + row norms (wave per row) ======
__global__ __launch_bounds__(256) void dkm_prepass(const float* __restrict__ X,
                                                   const float* __restrict__ C,
                                                   void* __restrict__ ws,
                                                   float* __restrict__ out) {
  _Float16* f16base = (_Float16*)ws;
  float* sqbase = (float*)(f16base + F16_TOTAL);  // xsq[NN] then csq[KK]

  if (blockIdx.x == 0 && threadIdx.x == 0) out[LOSS_OFF] = 0.0f;

  const int wave = threadIdx.x >> 6, lane = threadIdx.x & 63;
  const int row = blockIdx.x * 4 + wave;          // 4 rows/block, NN+KK rows total

  const float* src;
  _Float16 *hi, *lo;
  float* sqdst;
  if (row < NN) {
    src = X + (size_t)row * DD;
    hi = f16base + XHI_OFF + (size_t)row * DD;
    lo = f16base + XLO_OFF + (size_t)row * DD;
    sqdst = sqbase + row;
  } else {
    const int r = row - NN;
    src = C + (size_t)r * DD;
    hi = f16base + CHI_OFF + (size_t)r * DD;
    lo = f16base + CLO_OFF + (size_t)r * DD;
    sqdst = sqbase + NN + r;
  }

  float sum = 0.f;
  #pragma unroll
  for (int c = 0; c < 2; ++c) {
    const int off = (c * 64 + lane) * 4;          // float index
    const float4 v = *(const float4*)(src + off);
    f16x4 h, l;
    h[0] = (_Float16)v.x; l[0] = (_Float16)(v.x - (float)h[0]);
    h[1] = (_Float16)v.y; l[1] = (_Float16)(v.y - (float)h[1]);
    h[2] = (_Float16)v.z; l[2] = (_Float16)(v.z - (float)h[2]);
    h[3] = (_Float16)v.w; l[3] = (_Float16)(v.w - (float)h[3]);
    *(f16x4*)(hi + off) = h;
    *(f16x4*)(lo + off) = l;
    sum = fmaf(v.x, v.x, fmaf(v.y, v.y, fmaf(v.z, v.z, fmaf(v.w, v.w, sum))));
  }
  #pragma unroll
  for (int dm = 1; dm < 64; dm <<= 1) sum += __shfl_xor(sum, dm, 64);
  if (lane == 0) *sqdst = sum;
}

// ================= main: f16x3 MFMA distance + fused epilogue =================
// Block: 256 thr = 4 waves; tile 64 rows x 128 cols; wave grid 2x2 (32x64/wave).
// BD=32 -> one 16x16x32 K-step per stage; 128 stages. LDS in uint4 units with
// XOR swizzle u ^= ((row>>1)&3) (involution). DMA writes LINEAR units; the
// source chunk index is pre-swizzled instead (rule 21). 3 LDS buffers.
__global__ __launch_bounds__(256) void dkm_mfma(const void* __restrict__ ws,
                                                const float* __restrict__ C,
                                                float* __restrict__ out) {
  const _Float16* f16base = (const _Float16*)ws;
  const _Float16* Xhi = f16base + XHI_OFF;
  const _Float16* Xlo = f16base + XLO_OFF;
  const _Float16* Chi = f16base + CHI_OFF;
  const _Float16* Clo = f16base + CLO_OFF;
  const float* xsqw = (const float*)(f16base + F16_TOTAL);
  const float* csqw = xsqw + NN;

  __shared__ uint4 XsU[3][2][64 * 4];    // [buf][hi/lo][row*4 + kunit]  24.0 KB
  __shared__ uint4 CsU[3][2][128 * 4];   //                              48.0 KB
  __shared__ __align__(16) float csq[KK];
  __shared__ float xsq[64];
  __shared__ float sm_m[2][64], sm_s[2][64], sm_t[2][64];
  __shared__ int   sm_bi[2][64];
  __shared__ int   idx_lds[64];
  // total 80384 B -> exactly 157*512; 2 blocks/CU = 160768 <= 163840 OK

  const int t  = threadIdx.x;
  const int r0 = blockIdx.x * 64;

  // stage csq (4 KB) + this block's xsq
  *(float4*)&csq[t * 4] = *(const float4*)&csqw[t * 4];
  if (t < 64) xsq[t] = xsqw[r0 + t];

  const int wave = t >> 6, lane = t & 63;
  const int wr = wave >> 1, wc = wave & 1;   // wave tile: rows wr*32.., cols wc*64..
  const int g = lane >> 4, tx = lane & 15;

  // ---- per-thread DMA source offsets (pre-swizzled chunk index) ----
  const int xrow = wave * 16 + (lane >> 2);
  const int xq   = lane & 3;
  const size_t xsrc = (size_t)(r0 + xrow) * DD + (size_t)((xq ^ ((xrow >> 1) & 3)) * 8);
  const int xldsu = wave * 64;               // wave-uniform LDS unit base
  const int crow0 = wave * 32 + (lane >> 2);
  const int crow1 = crow0 + 16;
  const size_t csrc0 = (size_t)crow0 * DD + (size_t)((xq ^ ((crow0 >> 1) & 3)) * 8);
  const size_t csrc1 = (size_t)crow1 * DD + (size_t)((xq ^ ((crow1 >> 1) & 3)) * 8);
  const int cldsu0 = wave * 128, cldsu1 = wave * 128 + 64;

  float m_[2][4], s_[2][4], tt[2][4];
  int bi[2][4];
  #pragma unroll
  for (int mf = 0; mf < 2; ++mf)
    #pragma unroll
    for (int r = 0; r < 4; ++r) { m_[mf][r] = 3.0e38f; s_[mf][r] = 0.f; tt[mf][r] = 0.f; bi[mf][r] = 0; }

  #define STAGE(buf, c0s, d0s)                                                   \
    do {                                                                         \
      const size_t cadd = (size_t)(c0s) * DD + (size_t)(d0s);                    \
      gll16(Xhi + xsrc + (d0s), &XsU[buf][0][xldsu]);                            \
      gll16(Xlo + xsrc + (d0s), &XsU[buf][1][xldsu]);                            \
      gll16(Chi + csrc0 + cadd, &CsU[buf][0][cldsu0]);                           \
      gll16(Chi + csrc1 + cadd, &CsU[buf][0][cldsu1]);                           \
      gll16(Clo + csrc0 + cadd, &CsU[buf][1][cldsu0]);                           \
      gll16(Clo + csrc1 + cadd, &CsU[buf][1][cldsu1]);                           \
    } while (0)

  // prologue: stage tiles 0 and 1 (12 loads in flight); complete csq/xsq ds_writes
  STAGE(0, 0, 0);
  STAGE(1, 0, 32);
  asm volatile("s_waitcnt lgkmcnt(0)" ::: "memory");

  int cur = 0, tgt = 2;
  for (int ct = 0; ct < 8; ++ct) {
    const int c0 = ct * 128;
    f32x4 acc[2][4];
    #pragma unroll
    for (int mf = 0; mf < 2; ++mf)
      #pragma unroll
      for (int nf = 0; nf < 4; ++nf) acc[mf][nf] = (f32x4)0.f;

    for (int dc = 0; dc < 16; ++dc) {
      const int s = ct * 16 + dc;
      // retire the 6 loads of tile s (oldest); keep tile s+1's 6 in flight
      if (s < NSTG - 1) { asm volatile("s_waitcnt vmcnt(6)" ::: "memory"); }
      else              { asm volatile("s_waitcnt vmcnt(0)" ::: "memory"); }
      __builtin_amdgcn_s_barrier();       // all waves: buf cur fully written
      __builtin_amdgcn_sched_barrier(0);  // keep ds_reads below the barrier

      if (s + 2 < NSTG) {                 // issue tile s+2 into buf tgt (!= cur)
        const int ns = s + 2;
        STAGE(tgt, (ns >> 4) * 128, (ns & 15) * 32);
      }
      __builtin_amdgcn_sched_barrier(0);

      // fragments from buf cur: A lane -> row (lane&15), k = g*8 + j
      f16x8 ah[2], al[2], bh[4], bl[4];
      #pragma unroll
      for (int mf = 0; mf < 2; ++mf) {
        const int row = wr * 32 + mf * 16 + tx;
        const int u = (row * 4 + g) ^ ((row >> 1) & 3);
        ah[mf] = *(const f16x8*)&XsU[cur][0][u];
        al[mf] = *(const f16x8*)&XsU[cur][1][u];
      }
      #pragma unroll
      for (int nf = 0; nf < 4; ++nf) {
        const int row = wc * 64 + nf * 16 + tx;
        const int u = (row * 4 + g) ^ ((row >> 1) & 3);
        bh[nf] = *(const f16x8*)&CsU[cur][0][u];
        bl[nf] = *(const f16x8*)&CsU[cur][1][u];
      }
      __builtin_amdgcn_s_setprio(1);
      #pragma unroll
      for (int mf = 0; mf < 2; ++mf)
        #pragma unroll
        for (int nf = 0; nf < 4; ++nf) {
          acc[mf][nf] = __builtin_amdgcn_mfma_f32_16x16x32_f16(ah[mf], bh[nf], acc[mf][nf], 0, 0, 0);
          acc[mf][nf] = __builtin_amdgcn_mfma_f32_16x16x32_f16(ah[mf], bl[nf], acc[mf][nf], 0, 0, 0);
          acc[mf][nf] = __builtin_amdgcn_mfma_f32_16x16x32_f16(al[mf], bh[nf], acc[mf][nf], 0, 0, 0);
        }
      __builtin_amdgcn_s_setprio(0);

      cur = (cur == 2) ? 0 : cur + 1;
      tgt = (tgt == 2) ? 0 : tgt + 1;
    }

    // epilogue: D[row][col], col = nf*16 + tx, row = mf*16 + g*4 + reg
    #pragma unroll
    for (int mf = 0; mf < 2; ++mf) {
      #pragma unroll
      for (int r = 0; r < 4; ++r) {
        const int row_l = wr * 32 + mf * 16 + g * 4 + r;
        const float xq2 = xsq[row_l];
        float d2v[4];
        float lmin = 3.0e38f; int lidx = 0;
        #pragma unroll
        for (int nf = 0; nf < 4; ++nf) {
          const int col = c0 + wc * 64 + nf * 16 + tx;
          const float d = fmaf(-2.0f, acc[mf][nf][r], xq2 + csq[col]);
          d2v[nf] = d;
          if (d < lmin) { lmin = d; lidx = col; }  // first-min: index ascends with nf
        }
        #pragma unroll
        for (int dm = 1; dm < 16; dm <<= 1) {      // butterfly across the 16 col lanes
          const float ov = __shfl_xor(lmin, dm, 16);
          const int   oi = __shfl_xor(lidx, dm, 16);
          if (ov < lmin || (ov == lmin && oi < lidx)) { lmin = ov; lidx = oi; }
        }
        const float mnew  = fminf(m_[mf][r], lmin);
        const float scale = __expf(mnew - m_[mf][r]);  // first tile: exp(-inf)=0
        s_[mf][r] *= scale;
        tt[mf][r] *= scale;
        if (lmin < m_[mf][r]) bi[mf][r] = lidx;
        m_[mf][r] = mnew;
        #pragma unroll
        for (int nf = 0; nf < 4; ++nf) {
          const float e = __expf(mnew - d2v[nf]);      // alpha = 1
          s_[mf][r] += e;
          tt[mf][r]  = fmaf(e, d2v[nf], tt[mf][r]);
        }
      }
    }
  }

  // sum per-lane softmin partials across the 16 col lanes (round-2 NaN lesson)
  #pragma unroll
  for (int mf = 0; mf < 2; ++mf)
    #pragma unroll
    for (int r = 0; r < 4; ++r)
      #pragma unroll
      for (int dm = 1; dm < 16; dm <<= 1) {
        s_[mf][r] += __shfl_xor(s_[mf][r], dm, 16);
        tt[mf][r] += __shfl_xor(tt[mf][r], dm, 16);
      }

  // per-wave partials -> LDS (2 col-groups per row)
  if (tx == 0) {
    #pragma unroll
    for (int mf = 0; mf < 2; ++mf)
      #pragma unroll
      for (int r = 0; r < 4; ++r) {
        const int row_l = wr * 32 + mf * 16 + g * 4 + r;
        sm_m[wc][row_l]  = m_[mf][r];
        sm_s[wc][row_l]  = s_[mf][r];
        sm_t[wc][row_l]  = tt[mf][r];
        sm_bi[wc][row_l] = bi[mf][r];
      }
  }
  __syncthreads();

  // combine the two col-groups; emit idx + loss
  if (t < 64) {
    const float ma = sm_m[0][t], mb = sm_m[1][t];
    const float sa = sm_s[0][t], sb = sm_s[1][t];
    const float ta = sm_t[0][t], tb = sm_t[1][t];
    const int   ia = sm_bi[0][t], ib = sm_bi[1][t];
    const int best = (mb < ma || (mb == ma && ib < ia)) ? ib : ia;
    const float mn = fminf(ma, mb);
    const float ea = __expf(mn - ma), eb = __expf(mn - mb);
    const float ssum = sa * ea + sb * eb;
    const float tsum = ta * ea + tb * eb;
    idx_lds[t] = best;
    out[IDX_OFF + r0 + t] = (float)best;
    float lsum = tsum / ssum;
    #pragma unroll
    for (int dm = 1; dm < 64; dm <<= 1) lsum += __shfl_xor(lsum, dm, 64);
    if (t == 0) atomicAdd(out + LOSS_OFF, lsum * (1.0f / KK));
  }
  __syncthreads();

  // centroid gather: 64 rows x 512 floats, coalesced float4
  #pragma unroll 4
  for (int i = 0; i < 32; ++i) {
    const int pos = i * 1024 + t * 4;
    const int row = pos >> 9, col = pos & 511;
    const float4 v = *(const float4*)&C[(size_t)idx_lds[row] * DD + col];
    *(float4*)&out[(size_t)(r0 + row) * DD + col] = v;
  }
  #undef STAGE
}

// ================= fallback: round-2 fp32 kernel (passed, 692 us) =================
#define BM 64
#define BN 128
#define BD 32
#define NT (KK / BN)
#define NC (DD / BD)

__global__ __launch_bounds__(256) void dkm_fused(const float* __restrict__ X,
                                                 const float* __restrict__ C,
                                                 float* __restrict__ out) {
  __shared__ float Xs[BD][BM + 4];
  __shared__ float Cs[BD][BN + 4];
  __shared__ float csq[KK];
  __shared__ float xsq[BM];
  __shared__ int   idx_lds[BM];
  __shared__ float loss_lds;

  const int t  = threadIdx.x;
  const int r0 = blockIdx.x * BM;
  if (t == 0) loss_lds = 0.0f;
  {
    const int row4 = t >> 2, seg = t & 3;
    for (int pass = 0; pass < KK / 64; ++pass) {
      const int row = pass * 64 + row4;
      const float* src = C + (size_t)row * DD + seg * 128;
      float sum = 0.f;
      #pragma unroll 8
      for (int i = 0; i < 32; ++i) {
        float4 v = *(const float4*)(src + i * 4);
        sum = fmaf(v.x, v.x, fmaf(v.y, v.y, fmaf(v.z, v.z, fmaf(v.w, v.w, sum))));
      }
      sum += __shfl_xor(sum, 1, 4);
      sum += __shfl_xor(sum, 2, 4);
      if (seg == 0) csq[row] = sum;
    }
    {
      const float* src = X + (size_t)(r0 + row4) * DD + seg * 128;
      float sum = 0.f;
      #pragma unroll 8
      for (int i = 0; i < 32; ++i) {
        float4 v = *(const float4*)(src + i * 4);
        sum = fmaf(v.x, v.x, fmaf(v.y, v.y, fmaf(v.z, v.z, fmaf(v.w, v.w, sum))));
      }
      sum += __shfl_xor(sum, 1, 4);
      sum += __shfl_xor(sum, 2, 4);
      if (seg == 0) xsq[row4] = sum;
    }
  }
  __syncthreads();

  const int ty = t >> 4, tx = t & 15;
  float m[4], s[4], tt[4];
  int bi[4];
  #pragma unroll
  for (int i = 0; i < 4; ++i) { m[i] = 3.0e38f; s[i] = 0.f; tt[i] = 0.f; bi[i] = 0; }

  for (int ct = 0; ct < NT; ++ct) {
    const int c0 = ct * BN;
    float acc[4][8];
    #pragma unroll
    for (int i = 0; i < 4; ++i)
      #pragma unroll
      for (int j = 0; j < 8; ++j) acc[i][j] = 0.f;

    for (int dc = 0; dc < NC; ++dc) {
      const int d0 = dc * BD;
      __syncthreads();
      {
        const int row = t >> 2, seg = t & 3;
        const float* src = X + (size_t)(r0 + row) * DD + d0 + seg * 8;
        float4 v0 = *(const float4*)src;
        float4 v1 = *(const float4*)(src + 4);
        const int kb = seg * 8;
        Xs[kb + 0][row] = v0.x; Xs[kb + 1][row] = v0.y;
        Xs[kb + 2][row] = v0.z; Xs[kb + 3][row] = v0.w;
        Xs[kb + 4][row] = v1.x; Xs[kb + 5][row] = v1.y;
        Xs[kb + 6][row] = v1.z; Xs[kb + 7][row] = v1.w;
      }
      {
        const int row = t >> 1, seg = t & 1;
        const float* src = C + (size_t)(c0 + row) * DD + d0 + seg * 16;
        float4 v0 = *(const float4*)src;
        float4 v1 = *(const float4*)(src + 4);
        float4 v2 = *(const float4*)(src + 8);
        float4 v3 = *(const float4*)(src + 12);
        const int kb = seg * 16;
        Cs[kb +  0][row] = v0.x; Cs[kb +  1][row] = v0.y;
        Cs[kb +  2][row] = v0.z; Cs[kb +  3][row] = v0.w;
        Cs[kb +  4][row] = v1.x; Cs[kb +  5][row] = v1.y;
        Cs[kb +  6][row] = v1.z; Cs[kb +  7][row] = v1.w;
        Cs[kb +  8][row] = v2.x; Cs[kb +  9][row] = v2.y;
        Cs[kb + 10][row] = v2.z; Cs[kb + 11][row] = v2.w;
        Cs[kb + 12][row] = v3.x; Cs[kb + 13][row] = v3.y;
        Cs[kb + 14][row] = v3.z; Cs[kb + 15][row] = v3.w;
      }
      __syncthreads();
      #pragma unroll
      for (int kk = 0; kk < BD; ++kk) {
        const float4 av  = *(const float4*)&Xs[kk][ty * 4];
        const float4 bv0 = *(const float4*)&Cs[kk][tx * 8];
        const float4 bv1 = *(const float4*)&Cs[kk][tx * 8 + 4];
        const float a0 = av.x, a1 = av.y, a2 = av.z, a3 = av.w;
        acc[0][0] = fmaf(a0, bv0.x, acc[0][0]); acc[0][1] = fmaf(a0, bv0.y, acc[0][1]);
        acc[0][2] = fmaf(a0, bv0.z, acc[0][2]); acc[0][3] = fmaf(a0, bv0.w, acc[0][3]);
        acc[0][4] = fmaf(a0, bv1.x, acc[0][4]); acc[0][5] = fmaf(a0, bv1.y, acc[0][5]);
        acc[0][6] = fmaf(a0, bv1.z, acc[0][6]); acc[0][7] = fmaf(a0, bv1.w, acc[0][7]);
        acc[1][0] = fmaf(a1, bv0.x, acc[1][0]); acc[1][1] = fmaf(a1, bv0.y, acc[1][1]);
        acc[1][2] = fmaf(a1, bv0.z, acc[1][2]); acc[1][3] = fmaf(a1, bv0.w, acc[1][3]);
        acc[1][4] = fmaf(a1, bv1.x, acc[1][4]); acc[1][5] = fmaf(a1, bv1.y, acc[1][5]);
        acc[1][6] = fmaf(a1, bv1.z, acc[1][6]); acc[1][7] = fmaf(a1, bv1.w, acc[1][7]);
        acc[2][0] = fmaf(a2, bv0.x, acc[2][0]); acc[2][1] = fmaf(a2, bv0.y, acc[2][1]);
        acc[2][2] = fmaf(a2, bv0.z, acc[2][2]); acc[2][3] = fmaf(a2, bv0.w, acc[2][3]);
        acc[2][4] = fmaf(a2, bv1.x, acc[2][4]); acc[2][5] = fmaf(a2, bv1.y, acc[2][5]);
        acc[2][6] = fmaf(a2, bv1.z, acc[2][6]); acc[2][7] = fmaf(a2, bv1.w, acc[2][7]);
        acc[3][0] = fmaf(a3, bv0.x, acc[3][0]); acc[3][1] = fmaf(a3, bv0.y, acc[3][1]);
        acc[3][2] = fmaf(a3, bv0.z, acc[3][2]); acc[3][3] = fmaf(a3, bv0.w, acc[3][3]);
        acc[3][4] = fmaf(a3, bv1.x, acc[3][4]); acc[3][5] = fmaf(a3, bv1.y, acc[3][5]);
        acc[3][6] = fmaf(a3, bv1.z, acc[3][6]); acc[3][7] = fmaf(a3, bv1.w, acc[3][7]);
      }
    }

    float cq[8];
    #pragma unroll
    for (int j = 0; j < 8; ++j) cq[j] = csq[c0 + tx * 8 + j];
    #pragma unroll
    for (int i = 0; i < 4; ++i) {
      const float xq = xsq[ty * 4 + i];
      float d2[8];
      float lmin = 3.0e38f; int lidx = 0;
      #pragma unroll
      for (int j = 0; j < 8; ++j) {
        d2[j] = fmaf(-2.0f, acc[i][j], xq + cq[j]);
        if (d2[j] < lmin) { lmin = d2[j]; lidx = c0 + tx * 8 + j; }
      }
      #pragma unroll
      for (int dm = 1; dm < 16; dm <<= 1) {
        const float ov = __shfl_xor(lmin, dm, 16);
        const int   oi = __shfl_xor(lidx, dm, 16);
        if (ov < lmin || (ov == lmin && oi < lidx)) { lmin = ov; lidx = oi; }
      }
      const float mnew  = fminf(m[i], lmin);
      const float scale = __expf(mnew - m[i]);
      s[i]  *= scale;
      tt[i] *= scale;
      if (lmin < m[i]) bi[i] = lidx;
      m[i] = mnew;
      #pragma unroll
      for (int j = 0; j < 8; ++j) {
        const float e = __expf(mnew - d2[j]);
        s[i]  += e;
        tt[i]  = fmaf(e, d2[j], tt[i]);
      }
    }
  }

  #pragma unroll
  for (int i = 0; i < 4; ++i) {
    #pragma unroll
    for (int dm = 1; dm < 16; dm <<= 1) {
      s[i]  += __shfl_xor(s[i],  dm, 16);
      tt[i] += __shfl_xor(tt[i], dm, 16);
    }
  }

  if (tx == 0) {
    float lsum = 0.f;
    #pragma unroll
    for (int i = 0; i < 4; ++i) {
      const int row = ty * 4 + i;
      idx_lds[row] = bi[i];
      out[IDX_OFF + r0 + row] = (float)bi[i];
      lsum += tt[i] / s[i];
    }
    atomicAdd(&loss_lds, lsum);
  }
  __syncthreads();
  if (t == 0) atomicAdd(out + LOSS_OFF, loss_lds * (1.0f / KK));

  #pragma unroll 4
  for (int i = 0; i < 32; ++i) {
    const int pos = i * 1024 + t * 4;
    const int row = pos >> 9, col = pos & 511;
    const float4 v = *(const float4*)&C[(size_t)idx_lds[row] * DD + col];
    *(float4*)&out[(size_t)(r0 + row) * DD + col] = v;
  }
}

extern "C" void kernel_launch(void* const* d_in, const int* in_sizes, int n_in,
                              void* d_out, int out_size, void* d_ws, size_t ws_size,
                              hipStream_t stream) {
  const float* X = (const float*)d_in[0];     // (32768, 512) fp32
  const float* C = (const float*)d_in[1];     // (1024, 512)  fp32
  float* out = (float*)d_out;
  (void)in_sizes; (void)n_in; (void)out_size;

  if (ws_size >= WS_NEEDED) {
    dkm_prepass<<<dim3((NN + KK) / 4), dim3(256), 0, stream>>>(X, C, d_ws, out);
    dkm_mfma<<<dim3(NN / 64), dim3(256), 0, stream>>>(d_ws, C, out);
  } else {
    // workspace too small for f16 split arrays -> proven fp32 path
    hipMemsetAsync((char*)d_out + LOSS_OFF * sizeof(float), 0, sizeof(float), stream);
    dkm_fused<<<dim3(NN / BM), dim3(256), 0, stream>>>(X, C, out);
  }
}

// Round 6
// 259.002 us; speedup vs baseline: 1.0884x; 1.0884x over previous
//
#include <hip/hip_runtime.h>
#include <hip/hip_bf16.h>

// DKM fused (round 6): 8-wave 128x512 blocks (N-split x2, 16 waves/CU), fp32-X
// staging with in-register f16 hi/lo split, xsq folded out of the softmax path.
// d2 = xsq + csq - 2 X C^T ; q = csq - 2 X C^T has the same argmin/softmax;
// loss_row = xsq_row + sum(soft*q);  sum_rows xsq added once as a scalar.
// X.C^T via f16x3: Xhi.Chi + Xhi.Clo + Xlo.Chi (fp32 MFMA accum) — proven r3-r5.
// Out layout (float32): [centroids 32768*512][idx 32768][loss 1]

#define NN 32768
#define DD 512
#define KK 1024
#define IDX_OFF ((size_t)NN * DD)
#define LOSS_OFF ((size_t)NN * DD + NN)

typedef _Float16 f16x8 __attribute__((ext_vector_type(8)));
typedef _Float16 f16x4 __attribute__((ext_vector_type(4)));
typedef float f32x4 __attribute__((ext_vector_type(4)));

// ---- workspace layout ----
#define CHI_OFF ((size_t)0)                 // f16[KK*DD]
#define CLO_OFF ((size_t)KK * DD)           // f16[KK*DD]
#define F16_TOTAL ((size_t)2 * KK * DD)
// then csq f32[KK]; then part float4[NN*2] (m,s,t,bi) per (row, col-half)
#define WS_NEEDED (F16_TOTAL * 2 + (size_t)KK * 4 + (size_t)NN * 2 * 16)

__device__ __forceinline__ void gll16(const void* g, void* lds) {
  // async global->LDS DMA, 16B/lane; LDS dest = wave-uniform base + lane*16
  __builtin_amdgcn_global_load_lds((const __attribute__((address_space(1))) void*)g,
                                   (__attribute__((address_space(3))) void*)lds, 16, 0, 0);
}

// ================= prepass: C -> f16 hi/lo + csq (wave per row) =================
__global__ __launch_bounds__(256) void dkm_prepc(const float* __restrict__ C,
                                                 void* __restrict__ ws,
                                                 float* __restrict__ out) {
  _Float16* f16base = (_Float16*)ws;
  float* csq = (float*)(f16base + F16_TOTAL);
  if (blockIdx.x == 0 && threadIdx.x == 0) out[LOSS_OFF] = 0.0f;

  const int wave = threadIdx.x >> 6, lane = threadIdx.x & 63;
  const int row = blockIdx.x * 4 + wave;               // grid 256 -> rows 0..1023
  const float* src = C + (size_t)row * DD;
  _Float16* hi = f16base + CHI_OFF + (size_t)row * DD;
  _Float16* lo = f16base + CLO_OFF + (size_t)row * DD;

  float sum = 0.f;
  #pragma unroll
  for (int c = 0; c < 2; ++c) {
    const int off = (c * 64 + lane) * 4;
    const float4 v = *(const float4*)(src + off);
    f16x4 hq, lq;
    hq[0] = (_Float16)v.x; lq[0] = (_Float16)(v.x - (float)hq[0]);
    hq[1] = (_Float16)v.y; lq[1] = (_Float16)(v.y - (float)hq[1]);
    hq[2] = (_Float16)v.z; lq[2] = (_Float16)(v.z - (float)hq[2]);
    hq[3] = (_Float16)v.w; lq[3] = (_Float16)(v.w - (float)hq[3]);
    *(f16x4*)(hi + off) = hq;
    *(f16x4*)(lo + off) = lq;
    sum = fmaf(v.x, v.x, fmaf(v.y, v.y, fmaf(v.z, v.z, fmaf(v.w, v.w, sum))));
  }
  #pragma unroll
  for (int dm = 1; dm < 64; dm <<= 1) sum += __shfl_xor(sum, dm, 64);
  if (lane == 0) csq[row] = sum;
}

// ================= main: 128 rows x 512 cols per block, 8 waves =================
// wave (wr,wc) = (wave>>1, wave&1): rows wr*32+[0,32), cols wc*64 within each
// 128-col ct tile; ct=0..3 sweeps the block's 512-col half. BD=32, 64 stages.
// LDS: X fp32 [128 rows][8 x 16B units], unit ^= (row&7)  -> 2-way reads (free).
//      C f16  [128 cols][4 x 16B units], unit ^= ((col>>1)&3) -> 2-way (free).
// DMA writes linear units; SOURCE is pre-swizzled (rule 21, involution).
__global__ __launch_bounds__(512, 4) void dkm_mfma(const float* __restrict__ X,
                                                   const void* __restrict__ ws,
                                                   float* __restrict__ out) {
  const _Float16* f16base = (const _Float16*)ws;
  const _Float16* Chi = f16base + CHI_OFF;
  const _Float16* Clo = f16base + CLO_OFF;
  const float* csqg = (const float*)(f16base + F16_TOTAL);
  float4* part = (float4*)(csqg + KK);

  __shared__ uint4 XsU[2][1024];       // [buf][row*8+u]      32 KB
  __shared__ uint4 CsU[2][2][512];     // [buf][hi/lo][col*4+u] 32 KB
  __shared__ float sm_m[2][128], sm_s[2][128], sm_t[2][128];
  __shared__ int   sm_bi[2][128];
  __shared__ float xred[4];
  // total ~68.2 KB -> 2 blocks/CU = 16 waves/CU

  const int t  = threadIdx.x;
  const int r0 = blockIdx.x * 128;
  const int hbase = blockIdx.y * 512;              // col half

  const int wave = t >> 6, lane = t & 63;
  const int wr = wave >> 1, wc = wave & 1;
  const int g = lane >> 4, tx = lane & 15;

  // ---- DMA source offsets (pre-swizzled) ----
  const int xrow0 = (2 * wave + 0) * 8 + (lane >> 3);     // X: 16 insts of 8 rows
  const int xrow1 = (2 * wave + 1) * 8 + (lane >> 3);
  const size_t xsrc0 = (size_t)(r0 + xrow0) * DD + (size_t)(((lane & 7) ^ (xrow0 & 7)) * 4);
  const size_t xsrc1 = (size_t)(r0 + xrow1) * DD + (size_t)(((lane & 7) ^ (xrow1 & 7)) * 4);
  const int colg = wave * 16 + (lane >> 2);               // C: 8 insts of 16 cols
  const size_t csrc = (size_t)colg * DD + (size_t)(((lane & 3) ^ ((colg >> 1) & 3)) * 8);

  #define STAGE(buf, ctn, d0n)                                                  \
    do {                                                                        \
      gll16(X + xsrc0 + (d0n), &XsU[buf][(2 * wave + 0) * 64]);                 \
      gll16(X + xsrc1 + (d0n), &XsU[buf][(2 * wave + 1) * 64]);                 \
      const size_t coff = (size_t)(hbase + (ctn) * 128) * DD + (d0n);           \
      gll16(Chi + csrc + coff, &CsU[buf][0][wave * 64]);                        \
      gll16(Clo + csrc + coff, &CsU[buf][1][wave * 64]);                        \
    } while (0)

  float m_[2][4], s_[2][4], tt[2][4];
  int bi[2][4];
  #pragma unroll
  for (int mf = 0; mf < 2; ++mf)
    #pragma unroll
    for (int r = 0; r < 4; ++r) { m_[mf][r] = 3.0e38f; s_[mf][r] = 0.f; tt[mf][r] = 0.f; bi[mf][r] = 0; }
  float xacc = 0.f;   // sum of x^2 over staged fp32 X (x4 over ct repeats)

  // prologue: stage 0, full drain, barrier
  STAGE(0, 0, 0);
  asm volatile("s_waitcnt vmcnt(0) lgkmcnt(0)" ::: "memory");
  __builtin_amdgcn_s_barrier();
  __builtin_amdgcn_sched_barrier(0);

  int sbuf = 0;
  for (int ct = 0; ct < 4; ++ct) {
    f32x4 acc[2][4];
    #pragma unroll
    for (int mf = 0; mf < 2; ++mf)
      #pragma unroll
      for (int nf = 0; nf < 4; ++nf) acc[mf][nf] = (f32x4)0.f;

    for (int dc = 0; dc < 16; ++dc) {
      const int s = ct * 16 + dc;
      if (s < 63) {                    // depth-1: issue next stage, async
        const int ns = s + 1;
        STAGE(sbuf ^ 1, ns >> 4, (ns & 15) * 32);
      }
      __builtin_amdgcn_sched_barrier(0);

      // A fragments: fp32 -> f16 hi/lo in registers. row = tx, k = g*8+j.
      f16x8 ah[2], al[2];
      #pragma unroll
      for (int mf = 0; mf < 2; ++mf) {
        const int row_l = wr * 32 + mf * 16 + tx;
        const int s7 = row_l & 7;
        const f32x4 a0 = *(const f32x4*)&XsU[sbuf][row_l * 8 + ((2 * g) ^ s7)];
        const f32x4 a1 = *(const f32x4*)&XsU[sbuf][row_l * 8 + ((2 * g + 1) ^ s7)];
        f16x8 hv, lv;
        #pragma unroll
        for (int i = 0; i < 4; ++i) {
          const float v = a0[i];
          const _Float16 hh = (_Float16)v;
          hv[i] = hh; lv[i] = (_Float16)(v - (float)hh);
          xacc = fmaf(v, v, xacc);
        }
        #pragma unroll
        for (int i = 0; i < 4; ++i) {
          const float v = a1[i];
          const _Float16 hh = (_Float16)v;
          hv[4 + i] = hh; lv[4 + i] = (_Float16)(v - (float)hh);
          xacc = fmaf(v, v, xacc);
        }
        ah[mf] = hv; al[mf] = lv;
      }
      // B fragments: col = tx, k = g*8+j
      f16x8 bh[4], bl[4];
      #pragma unroll
      for (int nf = 0; nf < 4; ++nf) {
        const int col_l = wc * 64 + nf * 16 + tx;
        const int u = g ^ ((col_l >> 1) & 3);
        bh[nf] = *(const f16x8*)&CsU[sbuf][0][col_l * 4 + u];
        bl[nf] = *(const f16x8*)&CsU[sbuf][1][col_l * 4 + u];
      }
      __builtin_amdgcn_s_setprio(1);
      #pragma unroll
      for (int mf = 0; mf < 2; ++mf)
        #pragma unroll
        for (int nf = 0; nf < 4; ++nf) {
          acc[mf][nf] = __builtin_amdgcn_mfma_f32_16x16x32_f16(ah[mf], bh[nf], acc[mf][nf], 0, 0, 0);
          acc[mf][nf] = __builtin_amdgcn_mfma_f32_16x16x32_f16(ah[mf], bl[nf], acc[mf][nf], 0, 0, 0);
          acc[mf][nf] = __builtin_amdgcn_mfma_f32_16x16x32_f16(al[mf], bh[nf], acc[mf][nf], 0, 0, 0);
        }
      __builtin_amdgcn_s_setprio(0);

      asm volatile("s_waitcnt vmcnt(0)" ::: "memory");   // next-stage loads landed
      __builtin_amdgcn_s_barrier();
      __builtin_amdgcn_sched_barrier(0);
      sbuf ^= 1;
    }

    // ---- epilogue for this 128-col tile: q = csq - 2ab; argmin + online softmin
    float cq[4];
    #pragma unroll
    for (int nf = 0; nf < 4; ++nf)
      cq[nf] = csqg[hbase + ct * 128 + wc * 64 + nf * 16 + tx];
    #pragma unroll
    for (int mf = 0; mf < 2; ++mf) {
      #pragma unroll
      for (int r = 0; r < 4; ++r) {
        float qv[4];
        float lmin = 3.0e38f; int lidx = 0;
        #pragma unroll
        for (int nf = 0; nf < 4; ++nf) {
          const float q = fmaf(-2.0f, acc[mf][nf][r], cq[nf]);
          qv[nf] = q;
          const int col = hbase + ct * 128 + wc * 64 + nf * 16 + tx;
          if (q < lmin) { lmin = q; lidx = col; }   // first-min: strict <
        }
        #pragma unroll
        for (int dm = 1; dm < 16; dm <<= 1) {       // butterfly across 16 col lanes
          const float ov = __shfl_xor(lmin, dm, 16);
          const int   oi = __shfl_xor(lidx, dm, 16);
          if (ov < lmin || (ov == lmin && oi < lidx)) { lmin = ov; lidx = oi; }
        }
        const float mnew  = fminf(m_[mf][r], lmin);
        const float scale = __expf(mnew - m_[mf][r]);   // first tile: exp(-inf)=0
        s_[mf][r] *= scale;
        tt[mf][r] *= scale;
        if (lmin < m_[mf][r]) bi[mf][r] = lidx;
        m_[mf][r] = mnew;
        #pragma unroll
        for (int nf = 0; nf < 4; ++nf) {
          const float e = __expf(mnew - qv[nf]);        // alpha = 1
          s_[mf][r] += e;
          tt[mf][r]  = fmaf(e, qv[nf], tt[mf][r]);
        }
      }
    }
  }

  // sum per-lane softmin partials across the 16 col lanes (r2 NaN lesson)
  #pragma unroll
  for (int mf = 0; mf < 2; ++mf)
    #pragma unroll
    for (int r = 0; r < 4; ++r)
      #pragma unroll
      for (int dm = 1; dm < 16; dm <<= 1) {
        s_[mf][r] += __shfl_xor(s_[mf][r], dm, 16);
        tt[mf][r] += __shfl_xor(tt[mf][r], dm, 16);
      }

  if (tx == 0) {
    #pragma unroll
    for (int mf = 0; mf < 2; ++mf)
      #pragma unroll
      for (int r = 0; r < 4; ++r) {
        const int row_l = wr * 32 + mf * 16 + g * 4 + r;
        sm_m[wc][row_l]  = m_[mf][r];
        sm_s[wc][row_l]  = s_[mf][r];
        sm_t[wc][row_l]  = tt[mf][r];
        sm_bi[wc][row_l] = bi[mf][r];
      }
  }
  // block-local sum(x^2): wc==0 waves cover all (row,k) exactly once per ct
  #pragma unroll
  for (int dm = 1; dm < 64; dm <<= 1) xacc += __shfl_xor(xacc, dm, 64);
  if (wc == 0 && lane == 0) xred[wr] = xacc;
  __syncthreads();

  if (t < 128) {   // combine the two 64-col groups; one partial per (row, half)
    const float ma = sm_m[0][t], mb = sm_m[1][t];
    const int   ia = sm_bi[0][t], ib = sm_bi[1][t];
    const int best = (mb < ma || (mb == ma && ib < ia)) ? ib : ia;
    const float mn = fminf(ma, mb);
    const float ea = __expf(mn - ma), eb = __expf(mn - mb);
    float4 p;
    p.x = mn;
    p.y = sm_s[0][t] * ea + sm_s[1][t] * eb;
    p.z = sm_t[0][t] * ea + sm_t[1][t] * eb;
    p.w = __int_as_float(best);
    part[(size_t)(r0 + t) * 2 + blockIdx.y] = p;
  }
  if (t == 0 && blockIdx.y == 0)   // xsq contribution once (x0.25: ct repeats)
    atomicAdd(out + LOSS_OFF, (xred[0] + xred[1] + xred[2] + xred[3]) * (0.25f / KK));
  #undef STAGE
}

// ================= combine: merge halves, idx, loss, centroid gather =================
__global__ __launch_bounds__(256) void dkm_combine(const void* __restrict__ ws,
                                                   const float* __restrict__ C,
                                                   float* __restrict__ out) {
  const _Float16* f16base = (const _Float16*)ws;
  const float* csqg = (const float*)(f16base + F16_TOTAL);
  const float4* part = (const float4*)(csqg + KK);

  __shared__ int   idx_lds[128];
  __shared__ float lred[2];

  const int t = threadIdx.x, r0 = blockIdx.x * 128;
  float lsum = 0.f;
  if (t < 128) {
    const float4 p0 = part[(size_t)(r0 + t) * 2 + 0];
    const float4 p1 = part[(size_t)(r0 + t) * 2 + 1];
    const int i0 = __float_as_int(p0.w), i1 = __float_as_int(p1.w);
    const int best = (p1.x < p0.x || (p1.x == p0.x && i1 < i0)) ? i1 : i0;
    const float mn = fminf(p0.x, p1.x);
    const float e0 = __expf(mn - p0.x), e1 = __expf(mn - p1.x);
    const float ss = p0.y * e0 + p1.y * e1;
    const float ts = p0.z * e0 + p1.z * e1;
    idx_lds[t] = best;
    out[IDX_OFF + r0 + t] = (float)best;
    lsum = ts / ss;
  }
  #pragma unroll
  for (int dm = 1; dm < 64; dm <<= 1) lsum += __shfl_xor(lsum, dm, 64);
  if (t < 128 && (t & 63) == 0) lred[t >> 6] = lsum;
  __syncthreads();
  if (t == 0) atomicAdd(out + LOSS_OFF, (lred[0] + lred[1]) * (1.0f / KK));

  // gather: 128 rows x 512 floats, coalesced float4 (C is L2/L3-hot)
  #pragma unroll 4
  for (int i = 0; i < 64; ++i) {
    const int pos = i * 1024 + t * 4;
    const int row = pos >> 9, col = pos & 511;
    const float4 v = *(const float4*)&C[(size_t)idx_lds[row] * DD + col];
    *(float4*)&out[(size_t)(r0 + row) * DD + col] = v;
  }
}

// ================= fallback: round-2 fp32 kernel (passed, 692 us) =================
#define BM 64
#define BN 128
#define BD 32
#define NT (KK / BN)
#define NC (DD / BD)

__global__ __launch_bounds__(256) void dkm_fused(const float* __restrict__ X,
                                                 const float* __restrict__ C,
                                                 float* __restrict__ out) {
  __shared__ float Xs[BD][BM + 4];
  __shared__ float Cs[BD][BN + 4];
  __shared__ float csq[KK];
  __shared__ float xsq[BM];
  __shared__ int   idx_lds[BM];
  __shared__ float loss_lds;

  const int t  = threadIdx.x;
  const int r0 = blockIdx.x * BM;
  if (t == 0) loss_lds = 0.0f;
  {
    const int row4 = t >> 2, seg = t & 3;
    for (int pass = 0; pass < KK / 64; ++pass) {
      const int row = pass * 64 + row4;
      const float* src = C + (size_t)row * DD + seg * 128;
      float sum = 0.f;
      #pragma unroll 8
      for (int i = 0; i < 32; ++i) {
        float4 v = *(const float4*)(src + i * 4);
        sum = fmaf(v.x, v.x, fmaf(v.y, v.y, fmaf(v.z, v.z, fmaf(v.w, v.w, sum))));
      }
      sum += __shfl_xor(sum, 1, 4);
      sum += __shfl_xor(sum, 2, 4);
      if (seg == 0) csq[row] = sum;
    }
    {
      const float* src = X + (size_t)(r0 + row4) * DD + seg * 128;
      float sum = 0.f;
      #pragma unroll 8
      for (int i = 0; i < 32; ++i) {
        float4 v = *(const float4*)(src + i * 4);
        sum = fmaf(v.x, v.x, fmaf(v.y, v.y, fmaf(v.z, v.z, fmaf(v.w, v.w, sum))));
      }
      sum += __shfl_xor(sum, 1, 4);
      sum += __shfl_xor(sum, 2, 4);
      if (seg == 0) xsq[row4] = sum;
    }
  }
  __syncthreads();

  const int ty = t >> 4, tx = t & 15;
  float m[4], s[4], tt[4];
  int bi[4];
  #pragma unroll
  for (int i = 0; i < 4; ++i) { m[i] = 3.0e38f; s[i] = 0.f; tt[i] = 0.f; bi[i] = 0; }

  for (int ct = 0; ct < NT; ++ct) {
    const int c0 = ct * BN;
    float acc[4][8];
    #pragma unroll
    for (int i = 0; i < 4; ++i)
      #pragma unroll
      for (int j = 0; j < 8; ++j) acc[i][j] = 0.f;

    for (int dc = 0; dc < NC; ++dc) {
      const int d0 = dc * BD;
      __syncthreads();
      {
        const int row = t >> 2, seg = t & 3;
        const float* src = X + (size_t)(r0 + row) * DD + d0 + seg * 8;
        float4 v0 = *(const float4*)src;
        float4 v1 = *(const float4*)(src + 4);
        const int kb = seg * 8;
        Xs[kb + 0][row] = v0.x; Xs[kb + 1][row] = v0.y;
        Xs[kb + 2][row] = v0.z; Xs[kb + 3][row] = v0.w;
        Xs[kb + 4][row] = v1.x; Xs[kb + 5][row] = v1.y;
        Xs[kb + 6][row] = v1.z; Xs[kb + 7][row] = v1.w;
      }
      {
        const int row = t >> 1, seg = t & 1;
        const float* src = C + (size_t)(c0 + row) * DD + d0 + seg * 16;
        float4 v0 = *(const float4*)src;
        float4 v1 = *(const float4*)(src + 4);
        float4 v2 = *(const float4*)(src + 8);
        float4 v3 = *(const float4*)(src + 12);
        const int kb = seg * 16;
        Cs[kb +  0][row] = v0.x; Cs[kb +  1][row] = v0.y;
        Cs[kb +  2][row] = v0.z; Cs[kb +  3][row] = v0.w;
        Cs[kb +  4][row] = v1.x; Cs[kb +  5][row] = v1.y;
        Cs[kb +  6][row] = v1.z; Cs[kb +  7][row] = v1.w;
        Cs[kb +  8][row] = v2.x; Cs[kb +  9][row] = v2.y;
        Cs[kb + 10][row] = v2.z; Cs[kb + 11][row] = v2.w;
        Cs[kb + 12][row] = v3.x; Cs[kb + 13][row] = v3.y;
        Cs[kb + 14][row] = v3.z; Cs[kb + 15][row] = v3.w;
      }
      __syncthreads();
      #pragma unroll
      for (int kk = 0; kk < BD; ++kk) {
        const float4 av  = *(const float4*)&Xs[kk][ty * 4];
        const float4 bv0 = *(const float4*)&Cs[kk][tx * 8];
        const float4 bv1 = *(const float4*)&Cs[kk][tx * 8 + 4];
        const float a0 = av.x, a1 = av.y, a2 = av.z, a3 = av.w;
        acc[0][0] = fmaf(a0, bv0.x, acc[0][0]); acc[0][1] = fmaf(a0, bv0.y, acc[0][1]);
        acc[0][2] = fmaf(a0, bv0.z, acc[0][2]); acc[0][3] = fmaf(a0, bv0.w, acc[0][3]);
        acc[0][4] = fmaf(a0, bv1.x, acc[0][4]); acc[0][5] = fmaf(a0, bv1.y, acc[0][5]);
        acc[0][6] = fmaf(a0, bv1.z, acc[0][6]); acc[0][7] = fmaf(a0, bv1.w, acc[0][7]);
        acc[1][0] = fmaf(a1, bv0.x, acc[1][0]); acc[1][1] = fmaf(a1, bv0.y, acc[1][1]);
        acc[1][2] = fmaf(a1, bv0.z, acc[1][2]); acc[1][3] = fmaf(a1, bv0.w, acc[1][3]);
        acc[1][4] = fmaf(a1, bv1.x, acc[1][4]); acc[1][5] = fmaf(a1, bv1.y, acc[1][5]);
        acc[1][6] = fmaf(a1, bv1.z, acc[1][6]); acc[1][7] = fmaf(a1, bv1.w, acc[1][7]);
        acc[2][0] = fmaf(a2, bv0.x, acc[2][0]); acc[2][1] = fmaf(a2, bv0.y, acc[2][1]);
        acc[2][2] = fmaf(a2, bv0.z, acc[2][2]); acc[2][3] = fmaf(a2, bv0.w, acc[2][3]);
        acc[2][4] = fmaf(a2, bv1.x, acc[2][4]); acc[2][5] = fmaf(a2, bv1.y, acc[2][5]);
        acc[2][6] = fmaf(a2, bv1.z, acc[2][6]); acc[2][7] = fmaf(a2, bv1.w, acc[2][7]);
        acc[3][0] = fmaf(a3, bv0.x, acc[3][0]); acc[3][1] = fmaf(a3, bv0.y, acc[3][1]);
        acc[3][2] = fmaf(a3, bv0.z, acc[3][2]); acc[3][3] = fmaf(a3, bv0.w, acc[3][3]);
        acc[3][4] = fmaf(a3, bv1.x, acc[3][4]); acc[3][5] = fmaf(a3, bv1.y, acc[3][5]);
        acc[3][6] = fmaf(a3, bv1.z, acc[3][6]); acc[3][7] = fmaf(a3, bv1.w, acc[3][7]);
      }
    }

    float cq[8];
    #pragma unroll
    for (int j = 0; j < 8; ++j) cq[j] = csq[c0 + tx * 8 + j];
    #pragma unroll
    for (int i = 0; i < 4; ++i) {
      const float xq = xsq[ty * 4 + i];
      float d2[8];
      float lmin = 3.0e38f; int lidx = 0;
      #pragma unroll
      for (int j = 0; j < 8; ++j) {
        d2[j] = fmaf(-2.0f, acc[i][j], xq + cq[j]);
        if (d2[j] < lmin) { lmin = d2[j]; lidx = c0 + tx * 8 + j; }
      }
      #pragma unroll
      for (int dm = 1; dm < 16; dm <<= 1) {
        const float ov = __shfl_xor(lmin, dm, 16);
        const int   oi = __shfl_xor(lidx, dm, 16);
        if (ov < lmin || (ov == lmin && oi < lidx)) { lmin = ov; lidx = oi; }
      }
      const float mnew  = fminf(m[i], lmin);
      const float scale = __expf(mnew - m[i]);
      s[i]  *= scale;
      tt[i] *= scale;
      if (lmin < m[i]) bi[i] = lidx;
      m[i] = mnew;
      #pragma unroll
      for (int j = 0; j < 8; ++j) {
        const float e = __expf(mnew - d2[j]);
        s[i]  += e;
        tt[i]  = fmaf(e, d2[j], tt[i]);
      }
    }
  }

  #pragma unroll
  for (int i = 0; i < 4; ++i) {
    #pragma unroll
    for (int dm = 1; dm < 16; dm <<= 1) {
      s[i]  += __shfl_xor(s[i],  dm, 16);
      tt[i] += __shfl_xor(tt[i], dm, 16);
    }
  }

  if (tx == 0) {
    float lsum = 0.f;
    #pragma unroll
    for (int i = 0; i < 4; ++i) {
      const int row = ty * 4 + i;
      idx_lds[row] = bi[i];
      out[IDX_OFF + r0 + row] = (float)bi[i];
      lsum += tt[i] / s[i];
    }
    atomicAdd(&loss_lds, lsum);
  }
  __syncthreads();
  if (t == 0) atomicAdd(out + LOSS_OFF, loss_lds * (1.0f / KK));

  #pragma unroll 4
  for (int i = 0; i < 32; ++i) {
    const int pos = i * 1024 + t * 4;
    const int row = pos >> 9, col = pos & 511;
    const float4 v = *(const float4*)&C[(size_t)idx_lds[row] * DD + col];
    *(float4*)&out[(size_t)(r0 + row) * DD + col] = v;
  }
}

extern "C" void kernel_launch(void* const* d_in, const int* in_sizes, int n_in,
                              void* d_out, int out_size, void* d_ws, size_t ws_size,
                              hipStream_t stream) {
  const float* X = (const float*)d_in[0];     // (32768, 512) fp32
  const float* C = (const float*)d_in[1];     // (1024, 512)  fp32
  float* out = (float*)d_out;
  (void)in_sizes; (void)n_in; (void)out_size;

  if (ws_size >= WS_NEEDED) {
    dkm_prepc<<<dim3(KK / 4), dim3(256), 0, stream>>>(C, d_ws, out);
    dkm_mfma<<<dim3(NN / 128, 2), dim3(512), 0, stream>>>(X, d_ws, out);
    dkm_combine<<<dim3(NN / 128), dim3(256), 0, stream>>>(d_ws, C, out);
  } else {
    // workspace too small -> proven fp32 path
    hipMemsetAsync((char*)d_out + LOSS_OFF * sizeof(float), 0, sizeof(float), stream);
    dkm_fused<<<dim3(NN / BM), dim3(256), 0, stream>>>(X, C, out);
  }
}